// Round 15
// baseline (355.557 us; speedup 1.0000x reference)
//
#include <hip/hip_runtime.h>
#include <hip/hip_bf16.h>

#define NHITS   16384
#define NEDGES  262144
#define NGROUPS 512
#define HID     128
#define LAYERS  3
#define FFND    512
#define MAXDEG  64
#define GCAP    96

typedef __attribute__((ext_vector_type(8))) short bf16x8;
typedef __attribute__((ext_vector_type(8))) unsigned short ushort8;
typedef __attribute__((ext_vector_type(4))) float floatx4;

__device__ __forceinline__ float bf2f(ushort u) {
    return __uint_as_float(((unsigned)u) << 16);
}
__device__ __forceinline__ ushort f2bf(float f) {
    unsigned u = __float_as_uint(f);
    unsigned r = (u + 0x7FFFu + ((u >> 16) & 1u)) >> 16;
    return (ushort)r;
}

// async global->LDS, 16B per lane. LDS side must be wave-uniform base + lane*16.
__device__ __forceinline__ void gl2lds16(const ushort* gp, ushort* lp) {
    __builtin_amdgcn_global_load_lds(
        (const __attribute__((address_space(1))) unsigned int*)(gp),
        (__attribute__((address_space(3))) unsigned int*)(lp), 16, 0, 0);
}

// ---------------- weight transpose+convert (+ counter zeroing) ----------------

struct TD { const float* src; ushort* dst; int K; int N; };
struct TDs { TD d[14]; };

__global__ __launch_bounds__(256) void transpose_all(TDs tds, int* __restrict__ zbuf,
                                                     int ztotal) {
    __shared__ float lds[32][33];
    if (blockIdx.y == 0) {
        for (int gz = blockIdx.x * 256 + threadIdx.x; gz < ztotal; gz += 64 * 256)
            zbuf[gz] = 0;
    }
    TD d = tds.d[blockIdx.y];
    int tX = d.N >> 5;
    int tiles = (d.K >> 5) * tX;
    if ((int)blockIdx.x >= tiles) return;
    int tk = blockIdx.x / tX, tn = blockIdx.x % tX;
    int k0 = tk * 32, n0 = tn * 32;
    int r = threadIdx.x >> 5, c = threadIdx.x & 31;
#pragma unroll
    for (int i = 0; i < 4; ++i)
        lds[r + i * 8][c] = d.src[(size_t)(k0 + r + i * 8) * d.N + n0 + c];
    __syncthreads();
#pragma unroll
    for (int i = 0; i < 4; ++i) {
        int n = n0 + r + i * 8;
        d.dst[(size_t)n * d.K + k0 + c] = f2bf(lds[c][r + i * 8]);
    }
}

// ---------------- scatter (padded buckets, packed 16B metadata) + embed ----------------

__global__ __launch_bounds__(256) void scatter_embed(
        const int* __restrict__ src, const int* __restrict__ dst,
        const float* __restrict__ ea, const int* __restrict__ gidx,
        int* __restrict__ cnt, int* __restrict__ cnt2,
        int4* __restrict__ epk, int* __restrict__ hlist,
        const float* __restrict__ x, const float* __restrict__ embW,
        const float* __restrict__ embB, float* __restrict__ h,
        ushort* __restrict__ hb) {
    const int vb = blockIdx.x, t = threadIdx.x;
    if (vb < 1024) {
        int e = vb * 256 + t;
        int d = dst[e];
        int slot = atomicAdd(&cnt[d], 1);
        if (slot < MAXDEG) {
            const float* eap = ea + (size_t)e * 5;
            int4 m;
            m.x = src[e];
            m.y = (int)((unsigned)f2bf(eap[0]) | ((unsigned)f2bf(eap[1]) << 16));
            m.z = (int)((unsigned)f2bf(eap[2]) | ((unsigned)f2bf(eap[3]) << 16));
            m.w = (int)(unsigned)f2bf(eap[4]);
            epk[(size_t)d * MAXDEG + slot] = m;
        }
        if (e < NHITS) {
            int g = gidx[e];
            int slot2 = atomicAdd(&cnt2[g], 1);
            if (slot2 < GCAP) hlist[g * GCAP + slot2] = e;
        }
    } else {
        __shared__ float xs[2][32];
        int base = (vb - 1024) * 32;
        for (int it = 0; it < 16; ++it) {
            int i0 = base + it * 2;
            __syncthreads();
            if (t < 25) xs[0][t] = x[(size_t)i0 * 25 + t];
            else if (t >= 128 && t < 153) xs[1][t - 128] = x[(size_t)(i0 + 1) * 25 + (t - 128)];
            __syncthreads();
            int node = i0 + (t >> 7), c = t & 127;
            const float* xr = xs[t >> 7];
            float s = embB[c];
#pragma unroll
            for (int k = 0; k < 25; ++k) s += xr[k] * embW[k * HID + c];
            h[(size_t)node * HID + c] = s;
            hb[(size_t)node * HID + c] = f2bf(s);
        }
    }
}

// ---------------- bf16 MFMA GEMM (generic): C(MxN) = A @ Bt^T + bias ----------------

__global__ __launch_bounds__(256) void gemm_mfma_k(const ushort* __restrict__ A,
                                                   const ushort* __restrict__ Bt,
                                                   const float* __restrict__ bias,
                                                   ushort* __restrict__ C,
                                                   int N, int K, int relu) {
    __shared__ ushort As[128 * 32];
    __shared__ ushort Bs[128 * 32];
    const int t = threadIdx.x;
    const int lane = t & 63;
    const int w = t >> 6;
    const int wr = w >> 1, wc = w & 1;
    const int lm = lane & 15, q = lane >> 4;
    const int row0 = blockIdx.y * 128;
    const int col0 = blockIdx.x * 128;
    const int sr = t >> 2, sc = (t & 3) * 8;
    const int sr2 = (t + 256) >> 2, sc2 = ((t + 256) & 3) * 8;

    floatx4 acc[4][4] = {};
    for (int k0 = 0; k0 < K; k0 += 32) {
        gl2lds16(A + (size_t)(row0 + sr) * K + k0 + sc,   &As[t * 8]);
        gl2lds16(A + (size_t)(row0 + sr2) * K + k0 + sc2, &As[t * 8 + 2048]);
        gl2lds16(Bt + (size_t)(col0 + sr) * K + k0 + sc,   &Bs[t * 8]);
        gl2lds16(Bt + (size_t)(col0 + sr2) * K + k0 + sc2, &Bs[t * 8 + 2048]);
        __syncthreads();
        bf16x8 af[4], bf[4];
#pragma unroll
        for (int it = 0; it < 4; ++it)
            af[it] = *(const bf16x8*)&As[(wr * 64 + it * 16 + lm) * 32 + q * 8];
#pragma unroll
        for (int jt = 0; jt < 4; ++jt)
            bf[jt] = *(const bf16x8*)&Bs[(wc * 64 + jt * 16 + lm) * 32 + q * 8];
#pragma unroll
        for (int it = 0; it < 4; ++it)
#pragma unroll
            for (int jt = 0; jt < 4; ++jt)
                acc[it][jt] = __builtin_amdgcn_mfma_f32_16x16x32_bf16(
                    af[it], bf[jt], acc[it][jt], 0, 0, 0);
        __syncthreads();
    }
#pragma unroll
    for (int jt = 0; jt < 4; ++jt) {
        int col = col0 + wc * 64 + jt * 16 + lm;
        float bb = bias ? bias[col] : 0.f;
#pragma unroll
        for (int it = 0; it < 4; ++it)
#pragma unroll
            for (int r = 0; r < 4; ++r) {
                int row = row0 + wr * 64 + it * 16 + q * 4 + r;
                float o = acc[it][jt][r] + bb;
                if (relu) o = fmaxf(o, 0.f);
                C[(size_t)row * N + col] = f2bf(o);
            }
    }
}

// ---------------- qkv GEMM (layer 0 only): q -> qb, k|v -> kvb packed ----------------

__global__ __launch_bounds__(256) void gemm_qkv_k(const ushort* __restrict__ A,
                                                  const ushort* __restrict__ Bt,
                                                  const float* __restrict__ bias,
                                                  ushort* __restrict__ qb,
                                                  ushort* __restrict__ kvb,
                                                  int K) {
    __shared__ ushort As[128 * 32];
    __shared__ ushort Bs[128 * 32];
    const int t = threadIdx.x;
    const int lane = t & 63;
    const int w = t >> 6;
    const int wr = w >> 1, wc = w & 1;
    const int lm = lane & 15, q = lane >> 4;
    const int row0 = blockIdx.y * 128;
    const int col0 = blockIdx.x * 128;   // 0=q, 128/256=k,v
    const int sr = t >> 2, sc = (t & 3) * 8;
    const int sr2 = (t + 256) >> 2, sc2 = ((t + 256) & 3) * 8;

    floatx4 acc[4][4] = {};
    for (int k0 = 0; k0 < K; k0 += 32) {
        gl2lds16(A + (size_t)(row0 + sr) * K + k0 + sc,   &As[t * 8]);
        gl2lds16(A + (size_t)(row0 + sr2) * K + k0 + sc2, &As[t * 8 + 2048]);
        gl2lds16(Bt + (size_t)(col0 + sr) * K + k0 + sc,   &Bs[t * 8]);
        gl2lds16(Bt + (size_t)(col0 + sr2) * K + k0 + sc2, &Bs[t * 8 + 2048]);
        __syncthreads();
        bf16x8 af[4], bf[4];
#pragma unroll
        for (int it = 0; it < 4; ++it)
            af[it] = *(const bf16x8*)&As[(wr * 64 + it * 16 + lm) * 32 + q * 8];
#pragma unroll
        for (int jt = 0; jt < 4; ++jt)
            bf[jt] = *(const bf16x8*)&Bs[(wc * 64 + jt * 16 + lm) * 32 + q * 8];
#pragma unroll
        for (int it = 0; it < 4; ++it)
#pragma unroll
            for (int jt = 0; jt < 4; ++jt)
                acc[it][jt] = __builtin_amdgcn_mfma_f32_16x16x32_bf16(
                    af[it], bf[jt], acc[it][jt], 0, 0, 0);
        __syncthreads();
    }
#pragma unroll
    for (int jt = 0; jt < 4; ++jt) {
        int col = col0 + wc * 64 + jt * 16 + lm;
        float bb = bias[col];
#pragma unroll
        for (int it = 0; it < 4; ++it)
#pragma unroll
            for (int r = 0; r < 4; ++r) {
                int row = row0 + wr * 64 + it * 16 + q * 4 + r;
                ushort ob = f2bf(acc[it][jt][r] + bb);
                if (col < 128) qb[(size_t)row * 128 + col] = ob;
                else           kvb[(size_t)row * 256 + (col - 128)] = ob;
            }
    }
}

// ---------------- edge attention (standalone, high occupancy, packed kv + epk) ----------------

__global__ __launch_bounds__(256) void attn_kernel(const ushort* __restrict__ qb,
                                                   const ushort* __restrict__ kvb,
                                                   const int4* __restrict__ epk,
                                                   const int* __restrict__ cnt,
                                                   const float* __restrict__ We,
                                                   const float* __restrict__ be,
                                                   ushort* __restrict__ attnb) {
    __shared__ float WeS[640], beS[128];
    int t = threadIdx.x;
    for (int idx = t; idx < 640; idx += 256) WeS[idx] = We[idx];
    if (t < 128) beS[t] = be[t];
    __syncthreads();
    const int i = blockIdx.x * 4 + (t >> 6);
    const int lane = t & 63;
    const int grp = lane >> 4;
    const int cb = (lane & 15) * 8;
    float qv[8];
    {
        ushort8 qq = *(const ushort8*)(qb + (size_t)i * 128 + cb);
#pragma unroll
        for (int j = 0; j < 8; ++j) qv[j] = bf2f(qq[j]);
    }
    float pj[6];
#pragma unroll
    for (int k = 0; k < 5; ++k) {
        float s = 0.f;
#pragma unroll
        for (int j = 0; j < 8; ++j) s += qv[j] * WeS[k * 128 + cb + j];
        pj[k] = s;
    }
    {
        float sb = 0.f;
#pragma unroll
        for (int j = 0; j < 8; ++j) sb += qv[j] * beS[cb + j];
        pj[5] = sb;
    }
#pragma unroll
    for (int k = 0; k < 6; ++k) {
        pj[k] += __shfl_xor(pj[k], 1);
        pj[k] += __shfl_xor(pj[k], 2);
    }
    float S = 0.f, T0 = 0.f, T1 = 0.f, T2 = 0.f, T3 = 0.f, T4 = 0.f;
    float acc[8] = {};
    const int endc = min(cnt[i], MAXDEG);
    const size_t pbase = (size_t)i * MAXDEG;
    const float scale = 0.17677669529663687f;   // 1/sqrt(32)

#pragma unroll 4
    for (int p0 = 0; p0 < endc; p0 += 4) {
        int pp = p0 + grp;
        bool act = pp < endc;
        int slot = act ? pp : (endc - 1);
        int4 m = epk[pbase + slot];
        int s = m.x;
        float a0 = bf2f((ushort)((unsigned)m.y & 0xffffu));
        float a1 = bf2f((ushort)((unsigned)m.y >> 16));
        float a2 = bf2f((ushort)((unsigned)m.z & 0xffffu));
        float a3 = bf2f((ushort)((unsigned)m.z >> 16));
        float a4 = bf2f((ushort)((unsigned)m.w & 0xffffu));
        const ushort* srow = kvb + (size_t)s * 256;
        ushort8 kk = *(const ushort8*)(srow + cb);
        ushort8 vv = *(const ushort8*)(srow + 128 + cb);
        float part = 0.f;
#pragma unroll
        for (int j = 0; j < 8; ++j) part += qv[j] * bf2f(kk[j]);
        part += __shfl_xor(part, 1);   // q·k over this head's 4 lanes
        part += __shfl_xor(part, 2);
        float logit = (part + pj[5] + a0 * pj[0] + a1 * pj[1] + a2 * pj[2]
                       + a3 * pj[3] + a4 * pj[4]) * scale;
        float pe = act ? __expf(logit) : 0.f;
        S += pe;
        T0 += pe * a0; T1 += pe * a1; T2 += pe * a2; T3 += pe * a3; T4 += pe * a4;
#pragma unroll
        for (int j = 0; j < 8; ++j) acc[j] += pe * bf2f(vv[j]);
    }
#pragma unroll
    for (int j = 0; j < 8; ++j) {
        acc[j] += __shfl_xor(acc[j], 16);
        acc[j] += __shfl_xor(acc[j], 32);
    }
    S += __shfl_xor(S, 16);   S += __shfl_xor(S, 32);
    T0 += __shfl_xor(T0, 16); T0 += __shfl_xor(T0, 32);
    T1 += __shfl_xor(T1, 16); T1 += __shfl_xor(T1, 32);
    T2 += __shfl_xor(T2, 16); T2 += __shfl_xor(T2, 32);
    T3 += __shfl_xor(T3, 16); T3 += __shfl_xor(T3, 32);
    T4 += __shfl_xor(T4, 16); T4 += __shfl_xor(T4, 32);
    if (grp == 0) {
        float inv = 1.f / fmaxf(S, 1e-9f);
        ushort8 o;
#pragma unroll
        for (int j = 0; j < 8; ++j) {
            float wadd = WeS[cb + j] * T0 + WeS[128 + cb + j] * T1
                       + WeS[256 + cb + j] * T2 + WeS[384 + cb + j] * T3
                       + WeS[512 + cb + j] * T4 + beS[cb + j] * S;
            o[j] = f2bf((acc[j] + wadd) * inv);
        }
        *(ushort8*)(attnb + (size_t)i * HID + cb) = o;
    }
}

// ---------------- fused Wo+LN1+FFN1+FFN2+LN2 [+next-layer qkv], row-local ----------------
// 16-ROW TILES (grid 1024 = 3 blocks/CU, 12 waves/CU): all 4 waves share the 16
// rows; each wave covers 32 output cols (jt in {0,1}). 2x more independent
// barrier-groups than the 32-row version -> better latency overlap. VGPR
// prefetch pipeline and k-order preserved (per-element GEMM arithmetic
// bit-identical; LN partial-sum grouping differs trivially).

__global__ __launch_bounds__(256) void woffn_k(
        const ushort* __restrict__ attnb,
        const ushort* __restrict__ Wot, const float* __restrict__ bo,
        const float* __restrict__ ln1g, const float* __restrict__ ln1b,
        const ushort* __restrict__ W1t, const float* __restrict__ b1v,
        const ushort* __restrict__ W2t, const float* __restrict__ b2v,
        const float* __restrict__ ln2g, const float* __restrict__ ln2b,
        float* __restrict__ h,
        const ushort* __restrict__ Wqn, const float* __restrict__ bqn,
        ushort* __restrict__ qb, ushort* __restrict__ kvb) {
    __shared__ ushort As[16 * 136];      // A tile (attnb -> LN1 -> LN2 out), padded
    __shared__ ushort Bs[4 * 4096];      // full-K B tile: 4 slabs of [128 cols x 32 k]
    __shared__ ushort midc[16 * 136];    // FFN chunk intermediate, padded
    __shared__ float redS[64], redQ[64]; // [row(16) x wave(4)]
    const int t = threadIdx.x;
    const int lane = t & 63;
    const int w = t >> 6;                // wave 0..3 -> cols [w*32, w*32+32)
    const int lm = lane & 15, q = lane >> 4;
    const int row0 = blockIdx.x * 16;
    const int sr = t >> 2, sc = (t & 3) * 8;
    const int sr2 = (t + 256) >> 2, sc2 = ((t + 256) & 3) * 8;

    ushort8 pf[8];   // in-flight B tile (32 VGPRs)
    auto pref = [&](const ushort* Wt, int ldK, int koff) {
#pragma unroll
        for (int kc = 0; kc < 4; ++kc) {
            pf[kc * 2]     = *(const ushort8*)(Wt + (size_t)sr * ldK + koff + kc * 32 + sc);
            pf[kc * 2 + 1] = *(const ushort8*)(Wt + (size_t)sr2 * ldK + koff + kc * 32 + sc2);
        }
    };
    auto commit = [&]() {
#pragma unroll
        for (int kc = 0; kc < 4; ++kc) {
            *(ushort8*)&Bs[kc * 4096 + t * 8] = pf[kc * 2];
            *(ushort8*)&Bs[kc * 4096 + t * 8 + 2048] = pf[kc * 2 + 1];
        }
    };
    // K=128 MFMA from LDS A (16 rows, stride 136) vs staged Bs; acc[2] col-tiles
    auto gemmK = [&](const ushort* Alds, floatx4* acc) {
#pragma unroll
        for (int kc = 0; kc < 4; ++kc) {
            bf16x8 af = *(const bf16x8*)&Alds[lm * 136 + kc * 32 + q * 8];
#pragma unroll
            for (int jt = 0; jt < 2; ++jt) {
                bf16x8 bf = *(const bf16x8*)&Bs[kc * 4096 + (w * 32 + jt * 16 + lm) * 32 + q * 8];
                acc[jt] = __builtin_amdgcn_mfma_f32_16x16x32_bf16(af, bf, acc[jt], 0, 0, 0);
            }
        }
    };
    // row-wise LN reduce: psum/psq per r -> shfl over 16 lanes -> 4-wave LDS combine
    auto lnreduce = [&](float psum[4], float psq[4]) {
#pragma unroll
        for (int r = 0; r < 4; ++r) {
            float s = psum[r], ss = psq[r];
#pragma unroll
            for (int k = 1; k < 16; k <<= 1) {
                s += __shfl_xor(s, k, 16);
                ss += __shfl_xor(ss, k, 16);
            }
            psum[r] = s; psq[r] = ss;
        }
        if (lm == 0)
#pragma unroll
            for (int r = 0; r < 4; ++r) {
                int rl = q * 4 + r;
                redS[rl * 4 + w] = psum[r];
                redQ[rl * 4 + w] = psq[r];
            }
    };

    // === init: stage A tile (16x128, 1 chunk/thread) + first B tile (Wo) ===
    {
        int row = t >> 4, c8 = (t & 15) * 8;
        *(ushort8*)&As[row * 136 + c8] =
            *(const ushort8*)(attnb + (size_t)(row0 + row) * HID + c8);
    }
    pref(Wot, HID, 0);          // only unavoidable exposure
    __syncthreads();            // As visible (drains pf too)
    commit();                   // Bs = Wo
    __syncthreads();

    // === Phase 1: Wo GEMM (prefetch W1_0 during compute) ===
    pref(W1t, HID, 0);
    floatx4 accW[2] = {};
    gemmK(As, accW);

    // LN1 epilogue -> As (bf16) + o1 regs (fp32 residual)
    float o1[2][4];
    {
        float psum[4] = {}, psq[4] = {};
#pragma unroll
        for (int jt = 0; jt < 2; ++jt) {
            int col = w * 32 + jt * 16 + lm;
            float bb = bo[col];
#pragma unroll
            for (int r = 0; r < 4; ++r) {
                int row = row0 + q * 4 + r;
                float v = accW[jt][r] + bb + h[(size_t)row * HID + col];
                o1[jt][r] = v;
                psum[r] += v;
                psq[r] += v * v;
            }
        }
        lnreduce(psum, psq);
        __syncthreads();   // redS ready; As reads (gemmK) done before As writes below
#pragma unroll
        for (int r = 0; r < 4; ++r) {
            int rl = q * 4 + r;
            float tot = redS[rl * 4] + redS[rl * 4 + 1] + redS[rl * 4 + 2] + redS[rl * 4 + 3];
            float totq = redQ[rl * 4] + redQ[rl * 4 + 1] + redQ[rl * 4 + 2] + redQ[rl * 4 + 3];
            float mu = tot * (1.f / HID);
            float var = totq * (1.f / HID) - mu * mu;
            float rstd = rsqrtf(var + 1e-5f);
#pragma unroll
            for (int jt = 0; jt < 2; ++jt) {
                int col = w * 32 + jt * 16 + lm;
                float o = (o1[jt][r] - mu) * rstd * ln1g[col] + ln1b[col];
                o1[jt][r] = o;
                As[rl * 136 + col] = f2bf(o);
            }
        }
    }
    __syncthreads();   // As(LN1) visible; Bs(Wo) reads long done
    commit();          // Bs = W1_0 (pf latency covered by Wo gemm + LN1)
    __syncthreads();

    // === Phase 2: chunk-fused FFN1 -> midc -> FFN2 accumulate ===
    floatx4 acc2[2] = {};
    for (int nc = 0; nc < 4; ++nc) {
        pref(W2t, FFND, nc * 128);          // W2_nc in flight
        floatx4 acc1[2] = {};
        gemmK(As, acc1);                    // uses Bs = W1_nc
#pragma unroll
        for (int jt = 0; jt < 2; ++jt) {
            int col = w * 32 + jt * 16 + lm;
            float bb = b1v[nc * 128 + col];
#pragma unroll
            for (int r = 0; r < 4; ++r) {
                int row = q * 4 + r;
                midc[row * 136 + col] = f2bf(fmaxf(acc1[jt][r] + bb, 0.f));
            }
        }
        __syncthreads();   // midc visible; Bs(W1_nc) reads done (drains W2_nc pf, covered)
        commit();          // Bs = W2_nc
        __syncthreads();
        if (nc < 3) pref(W1t + (size_t)(nc + 1) * 128 * HID, HID, 0);
        else        pref(Wqn ? Wqn : Wot, HID, 0);   // Q0 (or harmless dummy)
        gemmK(midc, acc2);                  // uses Bs = W2_nc
        __syncthreads();   // Bs + midc reads done (drains next pf, covered)
        commit();          // Bs = W1_{nc+1} / Q0
        __syncthreads();
    }

    // FFN2 epilogue: + residual(o1) + LN2 -> h [+ As for qkv]
    {
        float psum[4] = {}, psq[4] = {};
#pragma unroll
        for (int jt = 0; jt < 2; ++jt) {
            int col = w * 32 + jt * 16 + lm;
            float bb = b2v[col];
#pragma unroll
            for (int r = 0; r < 4; ++r) {
                float v = acc2[jt][r] + bb + o1[jt][r];
                acc2[jt][r] = v;
                psum[r] += v;
                psq[r] += v * v;
            }
        }
        lnreduce(psum, psq);
        __syncthreads();   // redS ready; As reads (FFN1) long done
#pragma unroll
        for (int r = 0; r < 4; ++r) {
            int rl = q * 4 + r;
            float tot = redS[rl * 4] + redS[rl * 4 + 1] + redS[rl * 4 + 2] + redS[rl * 4 + 3];
            float totq = redQ[rl * 4] + redQ[rl * 4 + 1] + redQ[rl * 4 + 2] + redQ[rl * 4 + 3];
            float mu = tot * (1.f / HID);
            float var = totq * (1.f / HID) - mu * mu;
            float rstd = rsqrtf(var + 1e-5f);
            int row = row0 + rl;
#pragma unroll
            for (int jt = 0; jt < 2; ++jt) {
                int col = w * 32 + jt * 16 + lm;
                float o = (acc2[jt][r] - mu) * rstd * ln2g[col] + ln2b[col];
                h[(size_t)row * HID + col] = o;
                if (Wqn) As[rl * 136 + col] = f2bf(o);
            }
        }
    }
    if (!Wqn) return;
    __syncthreads();   // As(LN2) visible; Bs already = Q0

    // === Phase 3: next-layer qkv, 3 chunks (Bs starts with Q0) ===
    for (int nc = 0; nc < 3; ++nc) {
        if (nc < 2) pref(Wqn + (size_t)(nc + 1) * 128 * HID, HID, 0);
        floatx4 accq[2] = {};
        gemmK(As, accq);
#pragma unroll
        for (int jt = 0; jt < 2; ++jt) {
            int col = w * 32 + jt * 16 + lm;
            float bb = bqn[nc * 128 + col];
#pragma unroll
            for (int r = 0; r < 4; ++r) {
                int row = row0 + q * 4 + r;
                ushort ob = f2bf(accq[jt][r] + bb);
                if (nc == 0)      qb[(size_t)row * 128 + col] = ob;
                else if (nc == 1) kvb[(size_t)row * 256 + col] = ob;
                else              kvb[(size_t)row * 256 + 128 + col] = ob;
            }
        }
        if (nc < 2) {
            __syncthreads();   // Bs reads done (drains pf, covered by gemmK+stores)
            commit();
            __syncthreads();
        }
    }
}

// ---------------- pooling via padded group buckets ----------------

__global__ __launch_bounds__(128) void pool_group(const float* __restrict__ h,
                                                  const float* __restrict__ x,
                                                  const int* __restrict__ hlist,
                                                  const int* __restrict__ cnt2,
                                                  ushort* __restrict__ geb) {
    int g = blockIdx.x, c = threadIdx.x;
    int n = min(cnt2[g], GCAP);
    float mx = -INFINITY, sx = 0.f, sy = 0.f, cx = 0.f, cy = 0.f;
    for (int p = 0; p < n; ++p) {
        int i = hlist[g * GCAP + p];
        float hv = h[(size_t)i * HID + c];
        mx = fmaxf(mx, hv);
        int view = (int)x[(size_t)i * 25 + 3];
        if (view == 0) { sx += hv; cx += 1.f; }
        else if (view == 1) { sy += hv; cy += 1.f; }
    }
    float gm = (n > 0) ? mx : 0.f;
    float px = sx / fmaxf(cx, 1.f), py = sy / fmaxf(cy, 1.f);
    float hx = cx > 0.f ? 1.f : 0.f, hy = cy > 0.f ? 1.f : 0.f;
    float sf = px * hx + py * hy;
    float valid = fmaxf(hx + hy, 1.f);
    geb[g * 256 + c] = f2bf(sf / valid);
    geb[g * 256 + 128 + c] = f2bf(gm);
}

// ---------------- fused pairwise score + symmetrize + sigmoid + mask ----------------

__global__ __launch_bounds__(256) void score_final(const ushort* __restrict__ Cab,
                                                   const float* __restrict__ W2,
                                                   const float* __restrict__ b1v,
                                                   const float* __restrict__ b2,
                                                   const int* __restrict__ ev,
                                                   float* __restrict__ out) {
    int bi = blockIdx.y, bj = blockIdx.x;
    if (bj < bi) return;
    __shared__ float Ai[16][129], Bi[16][129], Aj[16][129], Bj[16][129];
    __shared__ float w2s[128], b1s[128];
    int t = threadIdx.y * 16 + threadIdx.x;
    int i0 = bi * 16, j0 = bj * 16;
    for (int idx = t; idx < 2048; idx += 256) {
        int r = idx >> 7, k = idx & 127;
        Ai[r][k] = bf2f(Cab[(size_t)(i0 + r) * 256 + k]);
        Bi[r][k] = bf2f(Cab[(size_t)(i0 + r) * 256 + 128 + k]);
        Aj[r][k] = bf2f(Cab[(size_t)(j0 + r) * 256 + k]);
        Bj[r][k] = bf2f(Cab[(size_t)(j0 + r) * 256 + 128 + k]);
    }
    if (t < 128) { w2s[t] = W2[t]; b1s[t] = b1v[t]; }
    __syncthreads();
    int tx = threadIdx.x, ty = threadIdx.y;
    float sij = 0.f, sji = 0.f;
#pragma unroll 4
    for (int k = 0; k < 128; ++k) {
        float pb = b1s[k], wk = w2s[k];
        sij += fmaxf(Ai[ty][k] + Bj[tx][k] + pb, 0.f) * wk;
        sji += fmaxf(Aj[tx][k] + Bi[ty][k] + pb, 0.f) * wk;
    }
    float z = 0.5f * (sij + sji) + b2[0];
    float sg = 1.f / (1.f + __expf(-z));
    int gi = i0 + ty, gj = j0 + tx;
    float res = (ev[gi] == ev[gj]) ? sg : 0.f;
    out[(size_t)gi * NGROUPS + gj] = res;
    out[(size_t)gj * NGROUPS + gi] = res;
}

// ---------------- launch ----------------

static inline char* align256(char* p) {
    return (char*)(((uintptr_t)p + 255) & ~(uintptr_t)255);
}

extern "C" void kernel_launch(void* const* d_in, const int* in_sizes, int n_in,
                              void* d_out, int out_size, void* d_ws, size_t ws_size,
                              hipStream_t stream) {
    const float* x    = (const float*)d_in[0];
    const int* eidx   = (const int*)d_in[1];
    const float* ea   = (const float*)d_in[2];
    const int* gidx   = (const int*)d_in[3];
    const int* ev     = (const int*)d_in[4];
    const float* embW = (const float*)d_in[5];
    const float* embB = (const float*)d_in[6];
    const float* Wqkv = (const float*)d_in[7];
    const float* bqkv = (const float*)d_in[8];
    const float* We   = (const float*)d_in[9];
    const float* be   = (const float*)d_in[10];
    const float* Wo   = (const float*)d_in[11];
    const float* bo   = (const float*)d_in[12];
    const float* ln1g = (const float*)d_in[13];
    const float* ln1b = (const float*)d_in[14];
    const float* W1   = (const float*)d_in[15];
    const float* b1   = (const float*)d_in[16];
    const float* W2   = (const float*)d_in[17];
    const float* b2   = (const float*)d_in[18];
    const float* ln2g = (const float*)d_in[19];
    const float* ln2b = (const float*)d_in[20];
    const float* affW1 = (const float*)d_in[21];
    const float* affb1 = (const float*)d_in[22];
    const float* affW2 = (const float*)d_in[23];
    const float* affb2 = (const float*)d_in[24];

    const int* src = eidx;
    const int* dst = eidx + NEDGES;

    char* p = (char*)d_ws;
    float* h    = (float*)p;            p += (size_t)NHITS * HID * 4;
    int* cnt    = (int*)p;              p += NHITS * 4;       // ┐ contiguous, zeroed
    int* cnt2   = (int*)p;              p += NGROUPS * 4;     // ┘ in transpose_all
    int* hlist  = (int*)p;              p += NGROUPS * GCAP * 4;
    p = align256(p);
    int4* epk   = (int4*)p;             p += (size_t)NHITS * MAXDEG * 16;
    ushort* hb    = (ushort*)p;         p += (size_t)NHITS * HID * 2;
    ushort* qb    = (ushort*)p;         p += (size_t)NHITS * 128 * 2;
    ushort* kvb   = (ushort*)p;         p += (size_t)NHITS * 256 * 2;
    ushort* attnb = (ushort*)p;         p += (size_t)NHITS * HID * 2;
    ushort* geb   = (ushort*)p;         p += (size_t)NGROUPS * 256 * 2;
    ushort* Cab   = (ushort*)p;         p += (size_t)NGROUPS * 256 * 2;
    p = align256(p);
    ushort* Wqkvt = (ushort*)p;         p += (size_t)LAYERS * 384 * HID * 2;
    ushort* Wot   = (ushort*)p;         p += (size_t)LAYERS * HID * HID * 2;
    ushort* W1t   = (ushort*)p;         p += (size_t)LAYERS * FFND * HID * 2;
    ushort* W2t   = (ushort*)p;         p += (size_t)LAYERS * HID * FFND * 2;
    ushort* W1abt = (ushort*)p;         p += (size_t)256 * 256 * 2;

    // --- weight conversions + counter zeroing, one launch ---
    TDs tds;
    for (int l = 0; l < LAYERS; ++l) {
        tds.d[l * 4 + 0] = { Wqkv + (size_t)l * HID * 384, Wqkvt + (size_t)l * 384 * HID, HID, 384 };
        tds.d[l * 4 + 1] = { Wo + (size_t)l * HID * HID,   Wot + (size_t)l * HID * HID,   HID, HID };
        tds.d[l * 4 + 2] = { W1 + (size_t)l * HID * FFND,  W1t + (size_t)l * FFND * HID,  HID, FFND };
        tds.d[l * 4 + 3] = { W2 + (size_t)l * FFND * HID,  W2t + (size_t)l * HID * FFND,  FFND, HID };
    }
    tds.d[12] = { affW1,             W1abt,             256, HID };
    tds.d[13] = { affW1 + 256 * HID, W1abt + 128 * 256, 256, HID };
    transpose_all<<<dim3(64, 14), 256, 0, stream>>>(tds, cnt, NHITS + NGROUPS);

    // --- padded-bucket scatter (packed metadata) + embed ---
    scatter_embed<<<1536, 256, 0, stream>>>(src, dst, ea, gidx, cnt, cnt2,
                                            epk, hlist, x, embW, embB, h, hb);

    // --- layer-0 qkv ---
    gemm_qkv_k<<<dim3(3, NHITS / 128), 256, 0, stream>>>(
        hb, Wqkvt, bqkv, qb, kvb, HID);

    // --- transformer layers: 2 dispatches each (qkv fused into woffn) ---
    for (int l = 0; l < LAYERS; ++l) {
        attn_kernel<<<NHITS / 4, 256, 0, stream>>>(
            qb, kvb, epk, cnt, We + (size_t)l * 5 * HID, be + l * HID, attnb);
        const ushort* Wqn = (l + 1 < LAYERS) ? Wqkvt + (size_t)(l + 1) * 384 * HID : nullptr;
        const float* bqn = (l + 1 < LAYERS) ? bqkv + (l + 1) * 384 : nullptr;
        woffn_k<<<NHITS / 16, 256, 0, stream>>>(
            attnb, Wot + (size_t)l * HID * HID, bo + l * HID,
            ln1g + l * HID, ln1b + l * HID,
            W1t + (size_t)l * FFND * HID, b1 + l * FFND,
            W2t + (size_t)l * HID * FFND, b2 + l * HID,
            ln2g + l * HID, ln2b + l * HID, h, Wqn, bqn, qb, kvb);
    }

    // --- pooling + affinity head ---
    pool_group<<<NGROUPS, 128, 0, stream>>>(h, x, hlist, cnt2, geb);
    gemm_mfma_k<<<dim3(2, NGROUPS / 128), 256, 0, stream>>>(
        geb, W1abt, nullptr, Cab, 256, 256, 0);
    score_final<<<dim3(NGROUPS / 16, NGROUPS / 16), dim3(16, 16), 0, stream>>>(
        Cab, affW2, affb1, affb2, ev, (float*)d_out);
}

// Round 16
// 344.374 us; speedup vs baseline: 1.0325x; 1.0325x over previous
//
#include <hip/hip_runtime.h>
#include <hip/hip_bf16.h>

#define NHITS   16384
#define NEDGES  262144
#define NGROUPS 512
#define HID     128
#define LAYERS  3
#define FFND    512
#define MAXDEG  64
#define GCAP    96

typedef __attribute__((ext_vector_type(8))) short bf16x8;
typedef __attribute__((ext_vector_type(8))) unsigned short ushort8;
typedef __attribute__((ext_vector_type(4))) float floatx4;

__device__ __forceinline__ float bf2f(ushort u) {
    return __uint_as_float(((unsigned)u) << 16);
}
__device__ __forceinline__ ushort f2bf(float f) {
    unsigned u = __float_as_uint(f);
    unsigned r = (u + 0x7FFFu + ((u >> 16) & 1u)) >> 16;
    return (ushort)r;
}

// async global->LDS, 16B per lane. LDS side must be wave-uniform base + lane*16.
__device__ __forceinline__ void gl2lds16(const ushort* gp, ushort* lp) {
    __builtin_amdgcn_global_load_lds(
        (const __attribute__((address_space(1))) unsigned int*)(gp),
        (__attribute__((address_space(3))) unsigned int*)(lp), 16, 0, 0);
}

// ---------------- weight transpose+convert (+ counter zeroing) ----------------

struct TD { const float* src; ushort* dst; int K; int N; };
struct TDs { TD d[14]; };

__global__ __launch_bounds__(256) void transpose_all(TDs tds, int* __restrict__ zbuf,
                                                     int ztotal) {
    __shared__ float lds[32][33];
    if (blockIdx.y == 0) {
        for (int gz = blockIdx.x * 256 + threadIdx.x; gz < ztotal; gz += 64 * 256)
            zbuf[gz] = 0;
    }
    TD d = tds.d[blockIdx.y];
    int tX = d.N >> 5;
    int tiles = (d.K >> 5) * tX;
    if ((int)blockIdx.x >= tiles) return;
    int tk = blockIdx.x / tX, tn = blockIdx.x % tX;
    int k0 = tk * 32, n0 = tn * 32;
    int r = threadIdx.x >> 5, c = threadIdx.x & 31;
#pragma unroll
    for (int i = 0; i < 4; ++i)
        lds[r + i * 8][c] = d.src[(size_t)(k0 + r + i * 8) * d.N + n0 + c];
    __syncthreads();
#pragma unroll
    for (int i = 0; i < 4; ++i) {
        int n = n0 + r + i * 8;
        d.dst[(size_t)n * d.K + k0 + c] = f2bf(lds[c][r + i * 8]);
    }
}

// ---------------- scatter (padded buckets) + embed + LAYER-0 QKV ----------------
// blocks 0..1023: edge scatter (+ hit->group scatter);
// blocks 1024..1535: embed 32 nodes -> h + LDS tile, then qkv GEMM -> qb/kvb.

__global__ __launch_bounds__(256) void scatter_embed_qkv(
        const int* __restrict__ src, const int* __restrict__ dst,
        const float* __restrict__ ea, const int* __restrict__ gidx,
        int* __restrict__ cnt, int* __restrict__ cnt2,
        int4* __restrict__ epk, int* __restrict__ hlist,
        const float* __restrict__ x, const float* __restrict__ embW,
        const float* __restrict__ embB, float* __restrict__ h,
        const ushort* __restrict__ Wq0, const float* __restrict__ bq0,
        ushort* __restrict__ qb, ushort* __restrict__ kvb) {
    __shared__ __align__(16) char smem[8704 + 4 * 8192];
    const int vb = blockIdx.x, t = threadIdx.x;
    if (vb < 1024) {
        int e = vb * 256 + t;
        int d = dst[e];
        int slot = atomicAdd(&cnt[d], 1);
        if (slot < MAXDEG) {
            const float* eap = ea + (size_t)e * 5;
            int4 m;
            m.x = src[e];
            m.y = (int)((unsigned)f2bf(eap[0]) | ((unsigned)f2bf(eap[1]) << 16));
            m.z = (int)((unsigned)f2bf(eap[2]) | ((unsigned)f2bf(eap[3]) << 16));
            m.w = (int)(unsigned)f2bf(eap[4]);
            epk[(size_t)d * MAXDEG + slot] = m;
        }
        if (e < NHITS) {
            int g = gidx[e];
            int slot2 = atomicAdd(&cnt2[g], 1);
            if (slot2 < GCAP) hlist[g * GCAP + slot2] = e;
        }
        return;
    }
    // ---- embed + qkv branch ----
    ushort* As = (ushort*)smem;               // 32 x 136 bf16
    ushort* Bs = (ushort*)(smem + 8704);      // 4 slabs x [128 x 32]
    float* xsF = (float*)(smem + 8704);       // overlaps Bs; dead before 1st commit
    const int base = (vb - 1024) * 32;

    for (int i = t; i < 32 * 25; i += 256) {
        int node = i / 25, k = i - node * 25;
        xsF[node * 26 + k] = x[(size_t)(base + node) * 25 + k];
    }
    __syncthreads();
    for (int i = t; i < 32 * 128; i += 256) {
        int node = i >> 7, c = i & 127;
        float s = embB[c];
#pragma unroll
        for (int k = 0; k < 25; ++k) s += xsF[node * 26 + k] * embW[k * HID + c];
        h[(size_t)(base + node) * HID + c] = s;
        As[node * 136 + c] = f2bf(s);
    }

    const int lane = t & 63;
    const int w = t >> 6;
    const int wr = w >> 1, wc = w & 1;
    const int lm = lane & 15, q = lane >> 4;
    const int sr = t >> 2, sc = (t & 3) * 8;
    const int sr2 = (t + 256) >> 2, sc2 = ((t + 256) & 3) * 8;

    for (int nc = 0; nc < 3; ++nc) {
        __syncthreads();   // As/xsF usage complete; prior Bs reads complete
#pragma unroll
        for (int kc = 0; kc < 4; ++kc) {
            gl2lds16(Wq0 + (size_t)(nc * 128 + sr) * HID + kc * 32 + sc,
                     &Bs[kc * 4096 + t * 8]);
            gl2lds16(Wq0 + (size_t)(nc * 128 + sr2) * HID + kc * 32 + sc2,
                     &Bs[kc * 4096 + t * 8 + 2048]);
        }
        __syncthreads();
        floatx4 accq[4] = {};
#pragma unroll
        for (int kc = 0; kc < 4; ++kc) {
            bf16x8 af = *(const bf16x8*)&As[(wr * 16 + lm) * 136 + kc * 32 + q * 8];
#pragma unroll
            for (int jt = 0; jt < 4; ++jt) {
                bf16x8 bf = *(const bf16x8*)&Bs[kc * 4096 + (wc * 64 + jt * 16 + lm) * 32 + q * 8];
                accq[jt] = __builtin_amdgcn_mfma_f32_16x16x32_bf16(af, bf, accq[jt], 0, 0, 0);
            }
        }
#pragma unroll
        for (int jt = 0; jt < 4; ++jt) {
            int col = wc * 64 + jt * 16 + lm;
            float bb = bq0[nc * 128 + col];
#pragma unroll
            for (int r = 0; r < 4; ++r) {
                int row = base + wr * 16 + q * 4 + r;
                ushort ob = f2bf(accq[jt][r] + bb);
                if (nc == 0)      qb[(size_t)row * 128 + col] = ob;
                else if (nc == 1) kvb[(size_t)row * 256 + col] = ob;
                else              kvb[(size_t)row * 256 + 128 + col] = ob;
            }
        }
    }
}

// ---------------- edge attention (standalone, high occupancy, packed kv + epk) ----------------

__global__ __launch_bounds__(256) void attn_kernel(const ushort* __restrict__ qb,
                                                   const ushort* __restrict__ kvb,
                                                   const int4* __restrict__ epk,
                                                   const int* __restrict__ cnt,
                                                   const float* __restrict__ We,
                                                   const float* __restrict__ be,
                                                   ushort* __restrict__ attnb) {
    __shared__ float WeS[640], beS[128];
    int t = threadIdx.x;
    for (int idx = t; idx < 640; idx += 256) WeS[idx] = We[idx];
    if (t < 128) beS[t] = be[t];
    __syncthreads();
    const int i = blockIdx.x * 4 + (t >> 6);
    const int lane = t & 63;
    const int grp = lane >> 4;
    const int cb = (lane & 15) * 8;
    float qv[8];
    {
        ushort8 qq = *(const ushort8*)(qb + (size_t)i * 128 + cb);
#pragma unroll
        for (int j = 0; j < 8; ++j) qv[j] = bf2f(qq[j]);
    }
    float pj[6];
#pragma unroll
    for (int k = 0; k < 5; ++k) {
        float s = 0.f;
#pragma unroll
        for (int j = 0; j < 8; ++j) s += qv[j] * WeS[k * 128 + cb + j];
        pj[k] = s;
    }
    {
        float sb = 0.f;
#pragma unroll
        for (int j = 0; j < 8; ++j) sb += qv[j] * beS[cb + j];
        pj[5] = sb;
    }
#pragma unroll
    for (int k = 0; k < 6; ++k) {
        pj[k] += __shfl_xor(pj[k], 1);
        pj[k] += __shfl_xor(pj[k], 2);
    }
    float S = 0.f, T0 = 0.f, T1 = 0.f, T2 = 0.f, T3 = 0.f, T4 = 0.f;
    float acc[8] = {};
    const int endc = min(cnt[i], MAXDEG);
    const size_t pbase = (size_t)i * MAXDEG;
    const float scale = 0.17677669529663687f;   // 1/sqrt(32)

#pragma unroll 4
    for (int p0 = 0; p0 < endc; p0 += 4) {
        int pp = p0 + grp;
        bool act = pp < endc;
        int slot = act ? pp : (endc - 1);
        int4 m = epk[pbase + slot];
        int s = m.x;
        float a0 = bf2f((ushort)((unsigned)m.y & 0xffffu));
        float a1 = bf2f((ushort)((unsigned)m.y >> 16));
        float a2 = bf2f((ushort)((unsigned)m.z & 0xffffu));
        float a3 = bf2f((ushort)((unsigned)m.z >> 16));
        float a4 = bf2f((ushort)((unsigned)m.w & 0xffffu));
        const ushort* srow = kvb + (size_t)s * 256;
        ushort8 kk = *(const ushort8*)(srow + cb);
        ushort8 vv = *(const ushort8*)(srow + 128 + cb);
        float part = 0.f;
#pragma unroll
        for (int j = 0; j < 8; ++j) part += qv[j] * bf2f(kk[j]);
        part += __shfl_xor(part, 1);   // q·k over this head's 4 lanes
        part += __shfl_xor(part, 2);
        float logit = (part + pj[5] + a0 * pj[0] + a1 * pj[1] + a2 * pj[2]
                       + a3 * pj[3] + a4 * pj[4]) * scale;
        float pe = act ? __expf(logit) : 0.f;
        S += pe;
        T0 += pe * a0; T1 += pe * a1; T2 += pe * a2; T3 += pe * a3; T4 += pe * a4;
#pragma unroll
        for (int j = 0; j < 8; ++j) acc[j] += pe * bf2f(vv[j]);
    }
#pragma unroll
    for (int j = 0; j < 8; ++j) {
        acc[j] += __shfl_xor(acc[j], 16);
        acc[j] += __shfl_xor(acc[j], 32);
    }
    S += __shfl_xor(S, 16);   S += __shfl_xor(S, 32);
    T0 += __shfl_xor(T0, 16); T0 += __shfl_xor(T0, 32);
    T1 += __shfl_xor(T1, 16); T1 += __shfl_xor(T1, 32);
    T2 += __shfl_xor(T2, 16); T2 += __shfl_xor(T2, 32);
    T3 += __shfl_xor(T3, 16); T3 += __shfl_xor(T3, 32);
    T4 += __shfl_xor(T4, 16); T4 += __shfl_xor(T4, 32);
    if (grp == 0) {
        float inv = 1.f / fmaxf(S, 1e-9f);
        ushort8 o;
#pragma unroll
        for (int j = 0; j < 8; ++j) {
            float wadd = WeS[cb + j] * T0 + WeS[128 + cb + j] * T1
                       + WeS[256 + cb + j] * T2 + WeS[384 + cb + j] * T3
                       + WeS[512 + cb + j] * T4 + beS[cb + j] * S;
            o[j] = f2bf((acc[j] + wadd) * inv);
        }
        *(ushort8*)(attnb + (size_t)i * HID + cb) = o;
    }
}

// ---------------- fused Wo+LN1+FFN1+FFN2+LN2 [+next-layer qkv] (round-13 best) ----------------
// FULL-K STAGING: each GEMM phase stages its whole 32KB B-tile in ONE burst +
// ONE barrier, then runs all 16 MFMAs barrier-free. 32-row tiles (grid 512).

__global__ __launch_bounds__(256) void woffn_k(
        const ushort* __restrict__ attnb,
        const ushort* __restrict__ Wot, const float* __restrict__ bo,
        const float* __restrict__ ln1g, const float* __restrict__ ln1b,
        const ushort* __restrict__ W1t, const float* __restrict__ b1v,
        const ushort* __restrict__ W2t, const float* __restrict__ b2v,
        const float* __restrict__ ln2g, const float* __restrict__ ln2b,
        float* __restrict__ h,
        const ushort* __restrict__ Wqn, const float* __restrict__ bqn,
        ushort* __restrict__ qb, ushort* __restrict__ kvb) {
    __shared__ ushort As[32 * 136];
    __shared__ ushort Bs[4 * 4096];
    __shared__ ushort midc[32 * 136];
    __shared__ float redS[64], redQ[64];
    const int t = threadIdx.x;
    const int lane = t & 63;
    const int w = t >> 6;
    const int wr = w >> 1, wc = w & 1;
    const int lm = lane & 15, q = lane >> 4;
    const int row0 = blockIdx.x * 32;
    const int sr = t >> 2, sc = (t & 3) * 8;
    const int sr2 = (t + 256) >> 2, sc2 = ((t + 256) & 3) * 8;

    auto stageB = [&](const ushort* Wt, int ldK, int koff) {
#pragma unroll
        for (int kc = 0; kc < 4; ++kc) {
            gl2lds16(Wt + (size_t)sr * ldK + koff + kc * 32 + sc,
                     &Bs[kc * 4096 + t * 8]);
            gl2lds16(Wt + (size_t)sr2 * ldK + koff + kc * 32 + sc2,
                     &Bs[kc * 4096 + t * 8 + 2048]);
        }
    };
    auto gemmK = [&](const ushort* Alds, floatx4* acc) {
#pragma unroll
        for (int kc = 0; kc < 4; ++kc) {
            bf16x8 af = *(const bf16x8*)&Alds[(wr * 16 + lm) * 136 + kc * 32 + q * 8];
#pragma unroll
            for (int jt = 0; jt < 4; ++jt) {
                bf16x8 bf = *(const bf16x8*)&Bs[kc * 4096 + (wc * 64 + jt * 16 + lm) * 32 + q * 8];
                acc[jt] = __builtin_amdgcn_mfma_f32_16x16x32_bf16(af, bf, acc[jt], 0, 0, 0);
            }
        }
    };

    for (int i = t; i < 32 * 16; i += 256) {
        int row = i >> 4, c8 = (i & 15) * 8;
        *(ushort8*)&As[row * 136 + c8] =
            *(const ushort8*)(attnb + (size_t)(row0 + row) * HID + c8);
    }
    stageB(Wot, HID, 0);
    __syncthreads();

    floatx4 accW[4] = {};
    gemmK(As, accW);

    float o1[4][4];
    {
        float psum[4] = {}, psq[4] = {};
#pragma unroll
        for (int jt = 0; jt < 4; ++jt) {
            int col = wc * 64 + jt * 16 + lm;
            float bb = bo[col];
#pragma unroll
            for (int r = 0; r < 4; ++r) {
                int row = row0 + wr * 16 + q * 4 + r;
                float v = accW[jt][r] + bb + h[(size_t)row * HID + col];
                o1[jt][r] = v;
                psum[r] += v;
                psq[r] += v * v;
            }
        }
#pragma unroll
        for (int r = 0; r < 4; ++r) {
            float s = psum[r], ss = psq[r];
#pragma unroll
            for (int k = 1; k < 16; k <<= 1) {
                s += __shfl_xor(s, k, 16);
                ss += __shfl_xor(ss, k, 16);
            }
            psum[r] = s; psq[r] = ss;
        }
        if (lm == 0)
#pragma unroll
            for (int r = 0; r < 4; ++r) {
                int rl = wr * 16 + q * 4 + r;
                redS[rl * 2 + wc] = psum[r];
                redQ[rl * 2 + wc] = psq[r];
            }
        __syncthreads();
#pragma unroll
        for (int r = 0; r < 4; ++r) {
            int rl = wr * 16 + q * 4 + r;
            float tot = redS[rl * 2] + redS[rl * 2 + 1];
            float totq = redQ[rl * 2] + redQ[rl * 2 + 1];
            float mu = tot * (1.f / HID);
            float var = totq * (1.f / HID) - mu * mu;
            float rstd = rsqrtf(var + 1e-5f);
#pragma unroll
            for (int jt = 0; jt < 4; ++jt) {
                int col = wc * 64 + jt * 16 + lm;
                float o = (o1[jt][r] - mu) * rstd * ln1g[col] + ln1b[col];
                o1[jt][r] = o;
                As[(wr * 16 + q * 4 + r) * 136 + col] = f2bf(o);
            }
        }
    }

    floatx4 acc2[4] = {};
    for (int nc = 0; nc < 4; ++nc) {
        __syncthreads();
        stageB(W1t + (size_t)nc * 128 * HID, HID, 0);
        __syncthreads();
        floatx4 acc1[4] = {};
        gemmK(As, acc1);
#pragma unroll
        for (int jt = 0; jt < 4; ++jt) {
            int col = wc * 64 + jt * 16 + lm;
            float bb = b1v[nc * 128 + col];
#pragma unroll
            for (int r = 0; r < 4; ++r) {
                int row = wr * 16 + q * 4 + r;
                midc[row * 136 + col] = f2bf(fmaxf(acc1[jt][r] + bb, 0.f));
            }
        }
        __syncthreads();
        stageB(W2t, FFND, nc * 128);
        __syncthreads();
        gemmK(midc, acc2);
    }

    {
        float psum[4] = {}, psq[4] = {};
#pragma unroll
        for (int jt = 0; jt < 4; ++jt) {
            int col = wc * 64 + jt * 16 + lm;
            float bb = b2v[col];
#pragma unroll
            for (int r = 0; r < 4; ++r) {
                float v = acc2[jt][r] + bb + o1[jt][r];
                acc2[jt][r] = v;
                psum[r] += v;
                psq[r] += v * v;
            }
        }
#pragma unroll
        for (int r = 0; r < 4; ++r) {
            float s = psum[r], ss = psq[r];
#pragma unroll
            for (int k = 1; k < 16; k <<= 1) {
                s += __shfl_xor(s, k, 16);
                ss += __shfl_xor(ss, k, 16);
            }
            psum[r] = s; psq[r] = ss;
        }
        if (lm == 0)
#pragma unroll
            for (int r = 0; r < 4; ++r) {
                int rl = wr * 16 + q * 4 + r;
                redS[rl * 2 + wc] = psum[r];
                redQ[rl * 2 + wc] = psq[r];
            }
        __syncthreads();
#pragma unroll
        for (int r = 0; r < 4; ++r) {
            int rl = wr * 16 + q * 4 + r;
            float tot = redS[rl * 2] + redS[rl * 2 + 1];
            float totq = redQ[rl * 2] + redQ[rl * 2 + 1];
            float mu = tot * (1.f / HID);
            float var = totq * (1.f / HID) - mu * mu;
            float rstd = rsqrtf(var + 1e-5f);
            int row = row0 + rl;
#pragma unroll
            for (int jt = 0; jt < 4; ++jt) {
                int col = wc * 64 + jt * 16 + lm;
                float o = (acc2[jt][r] - mu) * rstd * ln2g[col] + ln2b[col];
                h[(size_t)row * HID + col] = o;
                if (Wqn) As[rl * 136 + col] = f2bf(o);
            }
        }
    }
    if (!Wqn) return;

    for (int nc = 0; nc < 3; ++nc) {
        __syncthreads();
        stageB(Wqn + (size_t)nc * 128 * HID, HID, 0);
        __syncthreads();
        floatx4 accq[4] = {};
        gemmK(As, accq);
#pragma unroll
        for (int jt = 0; jt < 4; ++jt) {
            int col = wc * 64 + jt * 16 + lm;
            float bb = bqn[nc * 128 + col];
#pragma unroll
            for (int r = 0; r < 4; ++r) {
                int row = row0 + wr * 16 + q * 4 + r;
                ushort ob = f2bf(accq[jt][r] + bb);
                if (nc == 0)      qb[(size_t)row * 128 + col] = ob;
                else if (nc == 1) kvb[(size_t)row * 256 + col] = ob;
                else              kvb[(size_t)row * 256 + 128 + col] = ob;
            }
        }
    }
}

// ---------------- fused pooling + affinity GEMM: 2 groups/block -> Cab rows ----------------

__global__ __launch_bounds__(256) void pool_aff_k(const float* __restrict__ h,
                                                  const float* __restrict__ x,
                                                  const int* __restrict__ hlist,
                                                  const int* __restrict__ cnt2,
                                                  const ushort* __restrict__ W1abt,
                                                  ushort* __restrict__ Cab) {
    __shared__ float gebS[2][256];
    const int t = threadIdx.x;
    const int g0 = blockIdx.x * 2;
    {
        int gg = t >> 7, c = t & 127;
        int g = g0 + gg;
        int n = min(cnt2[g], GCAP);
        float mx = -INFINITY, sx = 0.f, sy = 0.f, cx = 0.f, cy = 0.f;
        for (int p = 0; p < n; ++p) {
            int i = hlist[g * GCAP + p];
            float hv = h[(size_t)i * HID + c];
            mx = fmaxf(mx, hv);
            int view = (int)x[(size_t)i * 25 + 3];
            if (view == 0) { sx += hv; cx += 1.f; }
            else if (view == 1) { sy += hv; cy += 1.f; }
        }
        float gm = (n > 0) ? mx : 0.f;
        float px = sx / fmaxf(cx, 1.f), py = sy / fmaxf(cy, 1.f);
        float hx = cx > 0.f ? 1.f : 0.f, hy = cy > 0.f ? 1.f : 0.f;
        float sf = px * hx + py * hy;
        float valid = fmaxf(hx + hy, 1.f);
        gebS[gg][c] = sf / valid;
        gebS[gg][128 + c] = gm;
    }
    __syncthreads();
    // Cab[g0+gg][t] = sum_k gebS[gg][k] * W1abt[t*256+k]
    float a0 = 0.f, a1 = 0.f;
    const ushort8* wrow = (const ushort8*)(W1abt + (size_t)t * 256);
#pragma unroll 8
    for (int kk = 0; kk < 32; ++kk) {
        ushort8 wv = wrow[kk];
#pragma unroll
        for (int j = 0; j < 8; ++j) {
            float wf = bf2f(wv[j]);
            a0 += gebS[0][kk * 8 + j] * wf;
            a1 += gebS[1][kk * 8 + j] * wf;
        }
    }
    Cab[(size_t)g0 * 256 + t] = f2bf(a0);
    Cab[(size_t)(g0 + 1) * 256 + t] = f2bf(a1);
}

// ---------------- fused pairwise score + symmetrize + sigmoid + mask ----------------

__global__ __launch_bounds__(256) void score_final(const ushort* __restrict__ Cab,
                                                   const float* __restrict__ W2,
                                                   const float* __restrict__ b1v,
                                                   const float* __restrict__ b2,
                                                   const int* __restrict__ ev,
                                                   float* __restrict__ out) {
    int bi = blockIdx.y, bj = blockIdx.x;
    if (bj < bi) return;
    __shared__ float Ai[16][129], Bi[16][129], Aj[16][129], Bj[16][129];
    __shared__ float w2s[128], b1s[128];
    int t = threadIdx.y * 16 + threadIdx.x;
    int i0 = bi * 16, j0 = bj * 16;
    for (int idx = t; idx < 2048; idx += 256) {
        int r = idx >> 7, k = idx & 127;
        Ai[r][k] = bf2f(Cab[(size_t)(i0 + r) * 256 + k]);
        Bi[r][k] = bf2f(Cab[(size_t)(i0 + r) * 256 + 128 + k]);
        Aj[r][k] = bf2f(Cab[(size_t)(j0 + r) * 256 + k]);
        Bj[r][k] = bf2f(Cab[(size_t)(j0 + r) * 256 + 128 + k]);
    }
    if (t < 128) { w2s[t] = W2[t]; b1s[t] = b1v[t]; }
    __syncthreads();
    int tx = threadIdx.x, ty = threadIdx.y;
    float sij = 0.f, sji = 0.f;
#pragma unroll 4
    for (int k = 0; k < 128; ++k) {
        float pb = b1s[k], wk = w2s[k];
        sij += fmaxf(Ai[ty][k] + Bj[tx][k] + pb, 0.f) * wk;
        sji += fmaxf(Aj[tx][k] + Bi[ty][k] + pb, 0.f) * wk;
    }
    float z = 0.5f * (sij + sji) + b2[0];
    float sg = 1.f / (1.f + __expf(-z));
    int gi = i0 + ty, gj = j0 + tx;
    float res = (ev[gi] == ev[gj]) ? sg : 0.f;
    out[(size_t)gi * NGROUPS + gj] = res;
    out[(size_t)gj * NGROUPS + gi] = res;
}

// ---------------- launch ----------------

static inline char* align256(char* p) {
    return (char*)(((uintptr_t)p + 255) & ~(uintptr_t)255);
}

extern "C" void kernel_launch(void* const* d_in, const int* in_sizes, int n_in,
                              void* d_out, int out_size, void* d_ws, size_t ws_size,
                              hipStream_t stream) {
    const float* x    = (const float*)d_in[0];
    const int* eidx   = (const int*)d_in[1];
    const float* ea   = (const float*)d_in[2];
    const int* gidx   = (const int*)d_in[3];
    const int* ev     = (const int*)d_in[4];
    const float* embW = (const float*)d_in[5];
    const float* embB = (const float*)d_in[6];
    const float* Wqkv = (const float*)d_in[7];
    const float* bqkv = (const float*)d_in[8];
    const float* We   = (const float*)d_in[9];
    const float* be   = (const float*)d_in[10];
    const float* Wo   = (const float*)d_in[11];
    const float* bo   = (const float*)d_in[12];
    const float* ln1g = (const float*)d_in[13];
    const float* ln1b = (const float*)d_in[14];
    const float* W1   = (const float*)d_in[15];
    const float* b1   = (const float*)d_in[16];
    const float* W2   = (const float*)d_in[17];
    const float* b2   = (const float*)d_in[18];
    const float* ln2g = (const float*)d_in[19];
    const float* ln2b = (const float*)d_in[20];
    const float* affW1 = (const float*)d_in[21];
    const float* affb1 = (const float*)d_in[22];
    const float* affW2 = (const float*)d_in[23];
    const float* affb2 = (const float*)d_in[24];

    const int* src = eidx;
    const int* dst = eidx + NEDGES;

    char* p = (char*)d_ws;
    float* h    = (float*)p;            p += (size_t)NHITS * HID * 4;
    int* cnt    = (int*)p;              p += NHITS * 4;       // ┐ contiguous, zeroed
    int* cnt2   = (int*)p;              p += NGROUPS * 4;     // ┘ in transpose_all
    int* hlist  = (int*)p;              p += NGROUPS * GCAP * 4;
    p = align256(p);
    int4* epk   = (int4*)p;             p += (size_t)NHITS * MAXDEG * 16;
    ushort* qb    = (ushort*)p;         p += (size_t)NHITS * 128 * 2;
    ushort* kvb   = (ushort*)p;         p += (size_t)NHITS * 256 * 2;
    ushort* attnb = (ushort*)p;         p += (size_t)NHITS * HID * 2;
    ushort* Cab   = (ushort*)p;         p += (size_t)NGROUPS * 256 * 2;
    p = align256(p);
    ushort* Wqkvt = (ushort*)p;         p += (size_t)LAYERS * 384 * HID * 2;
    ushort* Wot   = (ushort*)p;         p += (size_t)LAYERS * HID * HID * 2;
    ushort* W1t   = (ushort*)p;         p += (size_t)LAYERS * FFND * HID * 2;
    ushort* W2t   = (ushort*)p;         p += (size_t)LAYERS * HID * FFND * 2;
    ushort* W1abt = (ushort*)p;         p += (size_t)256 * 256 * 2;

    // --- weight conversions + counter zeroing, one launch ---
    TDs tds;
    for (int l = 0; l < LAYERS; ++l) {
        tds.d[l * 4 + 0] = { Wqkv + (size_t)l * HID * 384, Wqkvt + (size_t)l * 384 * HID, HID, 384 };
        tds.d[l * 4 + 1] = { Wo + (size_t)l * HID * HID,   Wot + (size_t)l * HID * HID,   HID, HID };
        tds.d[l * 4 + 2] = { W1 + (size_t)l * HID * FFND,  W1t + (size_t)l * FFND * HID,  HID, FFND };
        tds.d[l * 4 + 3] = { W2 + (size_t)l * FFND * HID,  W2t + (size_t)l * HID * FFND,  FFND, HID };
    }
    tds.d[12] = { affW1,             W1abt,             256, HID };
    tds.d[13] = { affW1 + 256 * HID, W1abt + 128 * 256, 256, HID };
    transpose_all<<<dim3(64, 14), 256, 0, stream>>>(tds, cnt, NHITS + NGROUPS);

    // --- scatter + embed + layer-0 qkv, one launch ---
    scatter_embed_qkv<<<1536, 256, 0, stream>>>(src, dst, ea, gidx, cnt, cnt2,
                                                epk, hlist, x, embW, embB, h,
                                                Wqkvt, bqkv, qb, kvb);

    // --- transformer layers: 2 dispatches each ---
    for (int l = 0; l < LAYERS; ++l) {
        attn_kernel<<<NHITS / 4, 256, 0, stream>>>(
            qb, kvb, epk, cnt, We + (size_t)l * 5 * HID, be + l * HID, attnb);
        const ushort* Wqn = (l + 1 < LAYERS) ? Wqkvt + (size_t)(l + 1) * 384 * HID : nullptr;
        const float* bqn = (l + 1 < LAYERS) ? bqkv + (l + 1) * 384 : nullptr;
        woffn_k<<<NHITS / 32, 256, 0, stream>>>(
            attnb, Wot + (size_t)l * HID * HID, bo + l * HID,
            ln1g + l * HID, ln1b + l * HID,
            W1t + (size_t)l * FFND * HID, b1 + l * FFND,
            W2t + (size_t)l * HID * FFND, b2 + l * HID,
            ln2g + l * HID, ln2b + l * HID, h, Wqn, bqn, qb, kvb);
    }

    // --- fused pooling + affinity GEMM, then score ---
    pool_aff_k<<<NGROUPS / 2, 256, 0, stream>>>(h, x, hlist, cnt2, W1abt, Cab);
    score_final<<<dim3(NGROUPS / 16, NGROUPS / 16), dim3(16, 16), 0, stream>>>(
        Cab, affW2, affb1, affb2, ev, (float*)d_out);
}

// Round 17
// 337.398 us; speedup vs baseline: 1.0538x; 1.0207x over previous
//
#include <hip/hip_runtime.h>
#include <hip/hip_bf16.h>

#define NHITS   16384
#define NEDGES  262144
#define NGROUPS 512
#define HID     128
#define LAYERS  3
#define FFND    512
#define MAXDEG  64
#define GCAP    96

typedef __attribute__((ext_vector_type(8))) short bf16x8;
typedef __attribute__((ext_vector_type(8))) unsigned short ushort8;
typedef __attribute__((ext_vector_type(4))) float floatx4;

__device__ __forceinline__ float bf2f(ushort u) {
    return __uint_as_float(((unsigned)u) << 16);
}
__device__ __forceinline__ ushort f2bf(float f) {
    unsigned u = __float_as_uint(f);
    unsigned r = (u + 0x7FFFu + ((u >> 16) & 1u)) >> 16;
    return (ushort)r;
}

// async global->LDS, 16B per lane. LDS side must be wave-uniform base + lane*16.
__device__ __forceinline__ void gl2lds16(const ushort* gp, ushort* lp) {
    __builtin_amdgcn_global_load_lds(
        (const __attribute__((address_space(1))) unsigned int*)(gp),
        (__attribute__((address_space(3))) unsigned int*)(lp), 16, 0, 0);
}

// ---------------- weight transpose+convert (+ counter zeroing) ----------------

struct TD { const float* src; ushort* dst; int K; int N; };
struct TDs { TD d[14]; };

__global__ __launch_bounds__(256) void transpose_all(TDs tds, int* __restrict__ zbuf,
                                                     int ztotal) {
    __shared__ float lds[32][33];
    if (blockIdx.y == 0) {
        for (int gz = blockIdx.x * 256 + threadIdx.x; gz < ztotal; gz += 64 * 256)
            zbuf[gz] = 0;
    }
    TD d = tds.d[blockIdx.y];
    int tX = d.N >> 5;
    int tiles = (d.K >> 5) * tX;
    if ((int)blockIdx.x >= tiles) return;
    int tk = blockIdx.x / tX, tn = blockIdx.x % tX;
    int k0 = tk * 32, n0 = tn * 32;
    int r = threadIdx.x >> 5, c = threadIdx.x & 31;
#pragma unroll
    for (int i = 0; i < 4; ++i)
        lds[r + i * 8][c] = d.src[(size_t)(k0 + r + i * 8) * d.N + n0 + c];
    __syncthreads();
#pragma unroll
    for (int i = 0; i < 4; ++i) {
        int n = n0 + r + i * 8;
        d.dst[(size_t)n * d.K + k0 + c] = f2bf(lds[c][r + i * 8]);
    }
}

// ---------------- scatter (padded buckets) + embed + LAYER-0 QKV ----------------

__global__ __launch_bounds__(256) void scatter_embed_qkv(
        const int* __restrict__ src, const int* __restrict__ dst,
        const float* __restrict__ ea, const int* __restrict__ gidx,
        int* __restrict__ cnt, int* __restrict__ cnt2,
        int4* __restrict__ epk, int* __restrict__ hlist,
        const float* __restrict__ x, const float* __restrict__ embW,
        const float* __restrict__ embB, float* __restrict__ h,
        const ushort* __restrict__ Wq0, const float* __restrict__ bq0,
        ushort* __restrict__ qb, ushort* __restrict__ kvb) {
    __shared__ __align__(16) char smem[8704 + 4 * 8192];
    const int vb = blockIdx.x, t = threadIdx.x;
    if (vb < 1024) {
        int e = vb * 256 + t;
        int d = dst[e];
        int slot = atomicAdd(&cnt[d], 1);
        if (slot < MAXDEG) {
            const float* eap = ea + (size_t)e * 5;
            int4 m;
            m.x = src[e];
            m.y = (int)((unsigned)f2bf(eap[0]) | ((unsigned)f2bf(eap[1]) << 16));
            m.z = (int)((unsigned)f2bf(eap[2]) | ((unsigned)f2bf(eap[3]) << 16));
            m.w = (int)(unsigned)f2bf(eap[4]);
            epk[(size_t)d * MAXDEG + slot] = m;
        }
        if (e < NHITS) {
            int g = gidx[e];
            int slot2 = atomicAdd(&cnt2[g], 1);
            if (slot2 < GCAP) hlist[g * GCAP + slot2] = e;
        }
        return;
    }
    // ---- embed + qkv branch ----
    ushort* As = (ushort*)smem;               // 32 x 136 bf16
    ushort* Bs = (ushort*)(smem + 8704);      // 4 slabs x [128 x 32]
    float* xsF = (float*)(smem + 8704);       // overlaps Bs; dead before 1st commit
    const int base = (vb - 1024) * 32;

    for (int i = t; i < 32 * 25; i += 256) {
        int node = i / 25, k = i - node * 25;
        xsF[node * 26 + k] = x[(size_t)(base + node) * 25 + k];
    }
    __syncthreads();
    for (int i = t; i < 32 * 128; i += 256) {
        int node = i >> 7, c = i & 127;
        float s = embB[c];
#pragma unroll
        for (int k = 0; k < 25; ++k) s += xsF[node * 26 + k] * embW[k * HID + c];
        h[(size_t)(base + node) * HID + c] = s;
        As[node * 136 + c] = f2bf(s);
    }

    const int lane = t & 63;
    const int w = t >> 6;
    const int wr = w >> 1, wc = w & 1;
    const int lm = lane & 15, q = lane >> 4;
    const int sr = t >> 2, sc = (t & 3) * 8;
    const int sr2 = (t + 256) >> 2, sc2 = ((t + 256) & 3) * 8;

    for (int nc = 0; nc < 3; ++nc) {
        __syncthreads();   // As/xsF usage complete; prior Bs reads complete
#pragma unroll
        for (int kc = 0; kc < 4; ++kc) {
            gl2lds16(Wq0 + (size_t)(nc * 128 + sr) * HID + kc * 32 + sc,
                     &Bs[kc * 4096 + t * 8]);
            gl2lds16(Wq0 + (size_t)(nc * 128 + sr2) * HID + kc * 32 + sc2,
                     &Bs[kc * 4096 + t * 8 + 2048]);
        }
        __syncthreads();
        floatx4 accq[4] = {};
#pragma unroll
        for (int kc = 0; kc < 4; ++kc) {
            bf16x8 af = *(const bf16x8*)&As[(wr * 16 + lm) * 136 + kc * 32 + q * 8];
#pragma unroll
            for (int jt = 0; jt < 4; ++jt) {
                bf16x8 bf = *(const bf16x8*)&Bs[kc * 4096 + (wc * 64 + jt * 16 + lm) * 32 + q * 8];
                accq[jt] = __builtin_amdgcn_mfma_f32_16x16x32_bf16(af, bf, accq[jt], 0, 0, 0);
            }
        }
#pragma unroll
        for (int jt = 0; jt < 4; ++jt) {
            int col = wc * 64 + jt * 16 + lm;
            float bb = bq0[nc * 128 + col];
#pragma unroll
            for (int r = 0; r < 4; ++r) {
                int row = base + wr * 16 + q * 4 + r;
                ushort ob = f2bf(accq[jt][r] + bb);
                if (nc == 0)      qb[(size_t)row * 128 + col] = ob;
                else if (nc == 1) kvb[(size_t)row * 256 + col] = ob;
                else              kvb[(size_t)row * 256 + 128 + col] = ob;
            }
        }
    }
}

// ---------------- edge attention (standalone, high occupancy, packed kv + epk) ----------------

__global__ __launch_bounds__(256) void attn_kernel(const ushort* __restrict__ qb,
                                                   const ushort* __restrict__ kvb,
                                                   const int4* __restrict__ epk,
                                                   const int* __restrict__ cnt,
                                                   const float* __restrict__ We,
                                                   const float* __restrict__ be,
                                                   ushort* __restrict__ attnb) {
    __shared__ float WeS[640], beS[128];
    int t = threadIdx.x;
    for (int idx = t; idx < 640; idx += 256) WeS[idx] = We[idx];
    if (t < 128) beS[t] = be[t];
    __syncthreads();
    const int i = blockIdx.x * 4 + (t >> 6);
    const int lane = t & 63;
    const int grp = lane >> 4;
    const int cb = (lane & 15) * 8;
    float qv[8];
    {
        ushort8 qq = *(const ushort8*)(qb + (size_t)i * 128 + cb);
#pragma unroll
        for (int j = 0; j < 8; ++j) qv[j] = bf2f(qq[j]);
    }
    float pj[6];
#pragma unroll
    for (int k = 0; k < 5; ++k) {
        float s = 0.f;
#pragma unroll
        for (int j = 0; j < 8; ++j) s += qv[j] * WeS[k * 128 + cb + j];
        pj[k] = s;
    }
    {
        float sb = 0.f;
#pragma unroll
        for (int j = 0; j < 8; ++j) sb += qv[j] * beS[cb + j];
        pj[5] = sb;
    }
#pragma unroll
    for (int k = 0; k < 6; ++k) {
        pj[k] += __shfl_xor(pj[k], 1);
        pj[k] += __shfl_xor(pj[k], 2);
    }
    float S = 0.f, T0 = 0.f, T1 = 0.f, T2 = 0.f, T3 = 0.f, T4 = 0.f;
    float acc[8] = {};
    const int endc = min(cnt[i], MAXDEG);
    const size_t pbase = (size_t)i * MAXDEG;
    const float scale = 0.17677669529663687f;   // 1/sqrt(32)

#pragma unroll 8
    for (int p0 = 0; p0 < endc; p0 += 4) {
        int pp = p0 + grp;
        bool act = pp < endc;
        int slot = act ? pp : (endc - 1);
        int4 m = epk[pbase + slot];
        int s = m.x;
        float a0 = bf2f((ushort)((unsigned)m.y & 0xffffu));
        float a1 = bf2f((ushort)((unsigned)m.y >> 16));
        float a2 = bf2f((ushort)((unsigned)m.z & 0xffffu));
        float a3 = bf2f((ushort)((unsigned)m.z >> 16));
        float a4 = bf2f((ushort)((unsigned)m.w & 0xffffu));
        const ushort* srow = kvb + (size_t)s * 256;
        ushort8 kk = *(const ushort8*)(srow + cb);
        ushort8 vv = *(const ushort8*)(srow + 128 + cb);
        float part = 0.f;
#pragma unroll
        for (int j = 0; j < 8; ++j) part += qv[j] * bf2f(kk[j]);
        part += __shfl_xor(part, 1);   // q·k over this head's 4 lanes
        part += __shfl_xor(part, 2);
        float logit = (part + pj[5] + a0 * pj[0] + a1 * pj[1] + a2 * pj[2]
                       + a3 * pj[3] + a4 * pj[4]) * scale;
        float pe = act ? __expf(logit) : 0.f;
        S += pe;
        T0 += pe * a0; T1 += pe * a1; T2 += pe * a2; T3 += pe * a3; T4 += pe * a4;
#pragma unroll
        for (int j = 0; j < 8; ++j) acc[j] += pe * bf2f(vv[j]);
    }
#pragma unroll
    for (int j = 0; j < 8; ++j) {
        acc[j] += __shfl_xor(acc[j], 16);
        acc[j] += __shfl_xor(acc[j], 32);
    }
    S += __shfl_xor(S, 16);   S += __shfl_xor(S, 32);
    T0 += __shfl_xor(T0, 16); T0 += __shfl_xor(T0, 32);
    T1 += __shfl_xor(T1, 16); T1 += __shfl_xor(T1, 32);
    T2 += __shfl_xor(T2, 16); T2 += __shfl_xor(T2, 32);
    T3 += __shfl_xor(T3, 16); T3 += __shfl_xor(T3, 32);
    T4 += __shfl_xor(T4, 16); T4 += __shfl_xor(T4, 32);
    if (grp == 0) {
        float inv = 1.f / fmaxf(S, 1e-9f);
        ushort8 o;
#pragma unroll
        for (int j = 0; j < 8; ++j) {
            float wadd = WeS[cb + j] * T0 + WeS[128 + cb + j] * T1
                       + WeS[256 + cb + j] * T2 + WeS[384 + cb + j] * T3
                       + WeS[512 + cb + j] * T4 + beS[cb + j] * S;
            o[j] = f2bf((acc[j] + wadd) * inv);
        }
        *(ushort8*)(attnb + (size_t)i * HID + cb) = o;
    }
}

// ---------------- fused Wo+LN1+FFN1+FFN2+LN2 [+next-layer qkv] ----------------
// FULL-K STAGING with COVERED ISSUE: every async B-tile stage is issued right
// after its "reads done" barrier and covered by the compute/stores that follow
// (LN part-B, midc stores, LN2 epilogue + h stores, qb/kvb stores).
// Accumulation order unchanged -> bit-identical to rounds 13/16.

__global__ __launch_bounds__(256) void woffn_k(
        const ushort* __restrict__ attnb,
        const ushort* __restrict__ Wot, const float* __restrict__ bo,
        const float* __restrict__ ln1g, const float* __restrict__ ln1b,
        const ushort* __restrict__ W1t, const float* __restrict__ b1v,
        const ushort* __restrict__ W2t, const float* __restrict__ b2v,
        const float* __restrict__ ln2g, const float* __restrict__ ln2b,
        float* __restrict__ h,
        const ushort* __restrict__ Wqn, const float* __restrict__ bqn,
        ushort* __restrict__ qb, ushort* __restrict__ kvb) {
    __shared__ ushort As[32 * 136];
    __shared__ ushort Bs[4 * 4096];
    __shared__ ushort midc[32 * 136];
    __shared__ float redS[64], redQ[64];
    const int t = threadIdx.x;
    const int lane = t & 63;
    const int w = t >> 6;
    const int wr = w >> 1, wc = w & 1;
    const int lm = lane & 15, q = lane >> 4;
    const int row0 = blockIdx.x * 32;
    const int sr = t >> 2, sc = (t & 3) * 8;
    const int sr2 = (t + 256) >> 2, sc2 = ((t + 256) & 3) * 8;

    auto stageB = [&](const ushort* Wt, int ldK, int koff) {
#pragma unroll
        for (int kc = 0; kc < 4; ++kc) {
            gl2lds16(Wt + (size_t)sr * ldK + koff + kc * 32 + sc,
                     &Bs[kc * 4096 + t * 8]);
            gl2lds16(Wt + (size_t)sr2 * ldK + koff + kc * 32 + sc2,
                     &Bs[kc * 4096 + t * 8 + 2048]);
        }
    };
    auto gemmK = [&](const ushort* Alds, floatx4* acc) {
#pragma unroll
        for (int kc = 0; kc < 4; ++kc) {
            bf16x8 af = *(const bf16x8*)&Alds[(wr * 16 + lm) * 136 + kc * 32 + q * 8];
#pragma unroll
            for (int jt = 0; jt < 4; ++jt) {
                bf16x8 bf = *(const bf16x8*)&Bs[kc * 4096 + (wc * 64 + jt * 16 + lm) * 32 + q * 8];
                acc[jt] = __builtin_amdgcn_mfma_f32_16x16x32_bf16(af, bf, acc[jt], 0, 0, 0);
            }
        }
    };

    for (int i = t; i < 32 * 16; i += 256) {
        int row = i >> 4, c8 = (i & 15) * 8;
        *(ushort8*)&As[row * 136 + c8] =
            *(const ushort8*)(attnb + (size_t)(row0 + row) * HID + c8);
    }
    stageB(Wot, HID, 0);
    __syncthreads();

    // === Phase 1: Wo GEMM ===
    floatx4 accW[4] = {};
    gemmK(As, accW);

    float o1[4][4];
    {
        float psum[4] = {}, psq[4] = {};
#pragma unroll
        for (int jt = 0; jt < 4; ++jt) {
            int col = wc * 64 + jt * 16 + lm;
            float bb = bo[col];
#pragma unroll
            for (int r = 0; r < 4; ++r) {
                int row = row0 + wr * 16 + q * 4 + r;
                float v = accW[jt][r] + bb + h[(size_t)row * HID + col];
                o1[jt][r] = v;
                psum[r] += v;
                psq[r] += v * v;
            }
        }
#pragma unroll
        for (int r = 0; r < 4; ++r) {
            float s = psum[r], ss = psq[r];
#pragma unroll
            for (int k = 1; k < 16; k <<= 1) {
                s += __shfl_xor(s, k, 16);
                ss += __shfl_xor(ss, k, 16);
            }
            psum[r] = s; psq[r] = ss;
        }
        if (lm == 0)
#pragma unroll
            for (int r = 0; r < 4; ++r) {
                int rl = wr * 16 + q * 4 + r;
                redS[rl * 2 + wc] = psum[r];
                redQ[rl * 2 + wc] = psq[r];
            }
        __syncthreads();     // redS ready; ALL waves' gemmK (As & Bs reads) done
        stageB(W1t, HID, 0); // issue W1_0, covered by LN part-B below
#pragma unroll
        for (int r = 0; r < 4; ++r) {
            int rl = wr * 16 + q * 4 + r;
            float tot = redS[rl * 2] + redS[rl * 2 + 1];
            float totq = redQ[rl * 2] + redQ[rl * 2 + 1];
            float mu = tot * (1.f / HID);
            float var = totq * (1.f / HID) - mu * mu;
            float rstd = rsqrtf(var + 1e-5f);
#pragma unroll
            for (int jt = 0; jt < 4; ++jt) {
                int col = wc * 64 + jt * 16 + lm;
                float o = (o1[jt][r] - mu) * rstd * ln1g[col] + ln1b[col];
                o1[jt][r] = o;
                As[(wr * 16 + q * 4 + r) * 136 + col] = f2bf(o);
            }
        }
    }
    __syncthreads();   // As(LN1) visible + W1_0 drained

    // === Phase 2: chunk-fused FFN1 -> midc -> FFN2 accumulate ===
    floatx4 acc2[4] = {};
    for (int nc = 0; nc < 4; ++nc) {
        floatx4 acc1[4] = {};
        gemmK(As, acc1);               // Bs = W1_nc
        __syncthreads();               // Bs reads done (all waves)
        stageB(W2t, FFND, nc * 128);   // issue W2_nc, covered by midc stores
#pragma unroll
        for (int jt = 0; jt < 4; ++jt) {
            int col = wc * 64 + jt * 16 + lm;
            float bb = b1v[nc * 128 + col];
#pragma unroll
            for (int r = 0; r < 4; ++r) {
                int row = wr * 16 + q * 4 + r;
                midc[row * 136 + col] = f2bf(fmaxf(acc1[jt][r] + bb, 0.f));
            }
        }
        __syncthreads();               // midc visible + W2_nc drained
        gemmK(midc, acc2);             // Bs = W2_nc
        if (nc < 3) {
            __syncthreads();           // Bs + midc reads done
            stageB(W1t + (size_t)(nc + 1) * 128 * HID, HID, 0);
            __syncthreads();           // drain (uncovered; structural)
        }
    }

    // FFN2 epilogue: + residual(o1) + LN2 -> h [+ As for qkv]; stage Q0 covered
    {
        float psum[4] = {}, psq[4] = {};
#pragma unroll
        for (int jt = 0; jt < 4; ++jt) {
            int col = wc * 64 + jt * 16 + lm;
            float bb = b2v[col];
#pragma unroll
            for (int r = 0; r < 4; ++r) {
                float v = acc2[jt][r] + bb + o1[jt][r];
                acc2[jt][r] = v;
                psum[r] += v;
                psq[r] += v * v;
            }
        }
#pragma unroll
        for (int r = 0; r < 4; ++r) {
            float s = psum[r], ss = psq[r];
#pragma unroll
            for (int k = 1; k < 16; k <<= 1) {
                s += __shfl_xor(s, k, 16);
                ss += __shfl_xor(ss, k, 16);
            }
            psum[r] = s; psq[r] = ss;
        }
        if (lm == 0)
#pragma unroll
            for (int r = 0; r < 4; ++r) {
                int rl = wr * 16 + q * 4 + r;
                redS[rl * 2 + wc] = psum[r];
                redQ[rl * 2 + wc] = psq[r];
            }
        __syncthreads();               // redS ready; gemmK(midc) reads done (all waves)
        if (Wqn) stageB(Wqn, HID, 0);  // issue Q0, covered by LN2 + h stores below
#pragma unroll
        for (int r = 0; r < 4; ++r) {
            int rl = wr * 16 + q * 4 + r;
            float tot = redS[rl * 2] + redS[rl * 2 + 1];
            float totq = redQ[rl * 2] + redQ[rl * 2 + 1];
            float mu = tot * (1.f / HID);
            float var = totq * (1.f / HID) - mu * mu;
            float rstd = rsqrtf(var + 1e-5f);
            int row = row0 + rl;
#pragma unroll
            for (int jt = 0; jt < 4; ++jt) {
                int col = wc * 64 + jt * 16 + lm;
                float o = (acc2[jt][r] - mu) * rstd * ln2g[col] + ln2b[col];
                h[(size_t)row * HID + col] = o;
                if (Wqn) As[rl * 136 + col] = f2bf(o);
            }
        }
    }
    if (!Wqn) return;
    __syncthreads();   // As(LN2) visible + Q0 drained

    // === Phase 3: next-layer qkv, 3 chunks (Bs = Q0 on entry) ===
    for (int nc = 0; nc < 3; ++nc) {
        floatx4 accq[4] = {};
        gemmK(As, accq);               // Bs = Q_nc
        if (nc < 2) {
            __syncthreads();           // Bs reads done
            stageB(Wqn + (size_t)(nc + 1) * 128 * HID, HID, 0);  // covered by stores
        }
#pragma unroll
        for (int jt = 0; jt < 4; ++jt) {
            int col = wc * 64 + jt * 16 + lm;
            float bb = bqn[nc * 128 + col];
#pragma unroll
            for (int r = 0; r < 4; ++r) {
                int row = row0 + wr * 16 + q * 4 + r;
                ushort ob = f2bf(accq[jt][r] + bb);
                if (nc == 0)      qb[(size_t)row * 128 + col] = ob;
                else if (nc == 1) kvb[(size_t)row * 256 + col] = ob;
                else              kvb[(size_t)row * 256 + 128 + col] = ob;
            }
        }
        if (nc < 2) __syncthreads();   // drain
    }
}

// ---------------- fused pooling + affinity GEMM: 2 groups/block -> Cab rows ----------------

__global__ __launch_bounds__(256) void pool_aff_k(const float* __restrict__ h,
                                                  const float* __restrict__ x,
                                                  const int* __restrict__ hlist,
                                                  const int* __restrict__ cnt2,
                                                  const ushort* __restrict__ W1abt,
                                                  ushort* __restrict__ Cab) {
    __shared__ float gebS[2][256];
    const int t = threadIdx.x;
    const int g0 = blockIdx.x * 2;
    {
        int gg = t >> 7, c = t & 127;
        int g = g0 + gg;
        int n = min(cnt2[g], GCAP);
        float mx = -INFINITY, sx = 0.f, sy = 0.f, cx = 0.f, cy = 0.f;
        for (int p = 0; p < n; ++p) {
            int i = hlist[g * GCAP + p];
            float hv = h[(size_t)i * HID + c];
            mx = fmaxf(mx, hv);
            int view = (int)x[(size_t)i * 25 + 3];
            if (view == 0) { sx += hv; cx += 1.f; }
            else if (view == 1) { sy += hv; cy += 1.f; }
        }
        float gm = (n > 0) ? mx : 0.f;
        float px = sx / fmaxf(cx, 1.f), py = sy / fmaxf(cy, 1.f);
        float hx = cx > 0.f ? 1.f : 0.f, hy = cy > 0.f ? 1.f : 0.f;
        float sf = px * hx + py * hy;
        float valid = fmaxf(hx + hy, 1.f);
        gebS[gg][c] = sf / valid;
        gebS[gg][128 + c] = gm;
    }
    __syncthreads();
    float a0 = 0.f, a1 = 0.f;
    const ushort8* wrow = (const ushort8*)(W1abt + (size_t)t * 256);
#pragma unroll 8
    for (int kk = 0; kk < 32; ++kk) {
        ushort8 wv = wrow[kk];
#pragma unroll
        for (int j = 0; j < 8; ++j) {
            float wf = bf2f(wv[j]);
            a0 += gebS[0][kk * 8 + j] * wf;
            a1 += gebS[1][kk * 8 + j] * wf;
        }
    }
    Cab[(size_t)g0 * 256 + t] = f2bf(a0);
    Cab[(size_t)(g0 + 1) * 256 + t] = f2bf(a1);
}

// ---------------- fused pairwise score + symmetrize + sigmoid + mask ----------------

__global__ __launch_bounds__(256) void score_final(const ushort* __restrict__ Cab,
                                                   const float* __restrict__ W2,
                                                   const float* __restrict__ b1v,
                                                   const float* __restrict__ b2,
                                                   const int* __restrict__ ev,
                                                   float* __restrict__ out) {
    int bi = blockIdx.y, bj = blockIdx.x;
    if (bj < bi) return;
    __shared__ float Ai[16][129], Bi[16][129], Aj[16][129], Bj[16][129];
    __shared__ float w2s[128], b1s[128];
    int t = threadIdx.y * 16 + threadIdx.x;
    int i0 = bi * 16, j0 = bj * 16;
    for (int idx = t; idx < 2048; idx += 256) {
        int r = idx >> 7, k = idx & 127;
        Ai[r][k] = bf2f(Cab[(size_t)(i0 + r) * 256 + k]);
        Bi[r][k] = bf2f(Cab[(size_t)(i0 + r) * 256 + 128 + k]);
        Aj[r][k] = bf2f(Cab[(size_t)(j0 + r) * 256 + k]);
        Bj[r][k] = bf2f(Cab[(size_t)(j0 + r) * 256 + 128 + k]);
    }
    if (t < 128) { w2s[t] = W2[t]; b1s[t] = b1v[t]; }
    __syncthreads();
    int tx = threadIdx.x, ty = threadIdx.y;
    float sij = 0.f, sji = 0.f;
#pragma unroll 4
    for (int k = 0; k < 128; ++k) {
        float pb = b1s[k], wk = w2s[k];
        sij += fmaxf(Ai[ty][k] + Bj[tx][k] + pb, 0.f) * wk;
        sji += fmaxf(Aj[tx][k] + Bi[ty][k] + pb, 0.f) * wk;
    }
    float z = 0.5f * (sij + sji) + b2[0];
    float sg = 1.f / (1.f + __expf(-z));
    int gi = i0 + ty, gj = j0 + tx;
    float res = (ev[gi] == ev[gj]) ? sg : 0.f;
    out[(size_t)gi * NGROUPS + gj] = res;
    out[(size_t)gj * NGROUPS + gi] = res;
}

// ---------------- launch ----------------

static inline char* align256(char* p) {
    return (char*)(((uintptr_t)p + 255) & ~(uintptr_t)255);
}

extern "C" void kernel_launch(void* const* d_in, const int* in_sizes, int n_in,
                              void* d_out, int out_size, void* d_ws, size_t ws_size,
                              hipStream_t stream) {
    const float* x    = (const float*)d_in[0];
    const int* eidx   = (const int*)d_in[1];
    const float* ea   = (const float*)d_in[2];
    const int* gidx   = (const int*)d_in[3];
    const int* ev     = (const int*)d_in[4];
    const float* embW = (const float*)d_in[5];
    const float* embB = (const float*)d_in[6];
    const float* Wqkv = (const float*)d_in[7];
    const float* bqkv = (const float*)d_in[8];
    const float* We   = (const float*)d_in[9];
    const float* be   = (const float*)d_in[10];
    const float* Wo   = (const float*)d_in[11];
    const float* bo   = (const float*)d_in[12];
    const float* ln1g = (const float*)d_in[13];
    const float* ln1b = (const float*)d_in[14];
    const float* W1   = (const float*)d_in[15];
    const float* b1   = (const float*)d_in[16];
    const float* W2   = (const float*)d_in[17];
    const float* b2   = (const float*)d_in[18];
    const float* ln2g = (const float*)d_in[19];
    const float* ln2b = (const float*)d_in[20];
    const float* affW1 = (const float*)d_in[21];
    const float* affb1 = (const float*)d_in[22];
    const float* affW2 = (const float*)d_in[23];
    const float* affb2 = (const float*)d_in[24];

    const int* src = eidx;
    const int* dst = eidx + NEDGES;

    char* p = (char*)d_ws;
    float* h    = (float*)p;            p += (size_t)NHITS * HID * 4;
    int* cnt    = (int*)p;              p += NHITS * 4;       // ┐ contiguous, zeroed
    int* cnt2   = (int*)p;              p += NGROUPS * 4;     // ┘ in transpose_all
    int* hlist  = (int*)p;              p += NGROUPS * GCAP * 4;
    p = align256(p);
    int4* epk   = (int4*)p;             p += (size_t)NHITS * MAXDEG * 16;
    ushort* qb    = (ushort*)p;         p += (size_t)NHITS * 128 * 2;
    ushort* kvb   = (ushort*)p;         p += (size_t)NHITS * 256 * 2;
    ushort* attnb = (ushort*)p;         p += (size_t)NHITS * HID * 2;
    ushort* Cab   = (ushort*)p;         p += (size_t)NGROUPS * 256 * 2;
    p = align256(p);
    ushort* Wqkvt = (ushort*)p;         p += (size_t)LAYERS * 384 * HID * 2;
    ushort* Wot   = (ushort*)p;         p += (size_t)LAYERS * HID * HID * 2;
    ushort* W1t   = (ushort*)p;         p += (size_t)LAYERS * FFND * HID * 2;
    ushort* W2t   = (ushort*)p;         p += (size_t)LAYERS * HID * FFND * 2;
    ushort* W1abt = (ushort*)p;         p += (size_t)256 * 256 * 2;

    // --- weight conversions + counter zeroing, one launch ---
    TDs tds;
    for (int l = 0; l < LAYERS; ++l) {
        tds.d[l * 4 + 0] = { Wqkv + (size_t)l * HID * 384, Wqkvt + (size_t)l * 384 * HID, HID, 384 };
        tds.d[l * 4 + 1] = { Wo + (size_t)l * HID * HID,   Wot + (size_t)l * HID * HID,   HID, HID };
        tds.d[l * 4 + 2] = { W1 + (size_t)l * HID * FFND,  W1t + (size_t)l * FFND * HID,  HID, FFND };
        tds.d[l * 4 + 3] = { W2 + (size_t)l * FFND * HID,  W2t + (size_t)l * HID * FFND,  FFND, HID };
    }
    tds.d[12] = { affW1,             W1abt,             256, HID };
    tds.d[13] = { affW1 + 256 * HID, W1abt + 128 * 256, 256, HID };
    transpose_all<<<dim3(64, 14), 256, 0, stream>>>(tds, cnt, NHITS + NGROUPS);

    // --- scatter + embed + layer-0 qkv, one launch ---
    scatter_embed_qkv<<<1536, 256, 0, stream>>>(src, dst, ea, gidx, cnt, cnt2,
                                                epk, hlist, x, embW, embB, h,
                                                Wqkvt, bqkv, qb, kvb);

    // --- transformer layers: 2 dispatches each ---
    for (int l = 0; l < LAYERS; ++l) {
        attn_kernel<<<NHITS / 4, 256, 0, stream>>>(
            qb, kvb, epk, cnt, We + (size_t)l * 5 * HID, be + l * HID, attnb);
        const ushort* Wqn = (l + 1 < LAYERS) ? Wqkvt + (size_t)(l + 1) * 384 * HID : nullptr;
        const float* bqn = (l + 1 < LAYERS) ? bqkv + (l + 1) * 384 : nullptr;
        woffn_k<<<NHITS / 32, 256, 0, stream>>>(
            attnb, Wot + (size_t)l * HID * HID, bo + l * HID,
            ln1g + l * HID, ln1b + l * HID,
            W1t + (size_t)l * FFND * HID, b1 + l * FFND,
            W2t + (size_t)l * HID * FFND, b2 + l * HID,
            ln2g + l * HID, ln2b + l * HID, h, Wqn, bqn, qb, kvb);
    }

    // --- fused pooling + affinity GEMM, then score ---
    pool_aff_k<<<NGROUPS / 2, 256, 0, stream>>>(h, x, hlist, cnt2, W1abt, Cab);
    score_final<<<dim3(NGROUPS / 16, NGROUPS / 16), dim3(16, 16), 0, stream>>>(
        Cab, affW2, affb1, affb2, ev, (float*)d_out);
}